// Round 19
// baseline (137.636 us; speedup 1.0000x reference)
//
#include <hip/hip_runtime.h>
#include <hip/hip_bf16.h>

typedef __hip_bfloat16 bf16;
typedef short bf16x8 __attribute__((ext_vector_type(8)));
typedef float f32x4 __attribute__((ext_vector_type(4)));

static __device__ __forceinline__ unsigned short f2bf(float f) {
    unsigned u = __float_as_uint(f);
    return (unsigned short)((u + 0x7fffu + ((u >> 16) & 1u)) >> 16);
}
static __device__ __forceinline__ unsigned pack2(float lo, float hi) {
    return (((unsigned)f2bf(hi)) << 16) | (unsigned)f2bf(lo);
}

// ---------------------------------------------------------------------------
// Kernel 1: separable positional-encoding tables (all f32).
// ---------------------------------------------------------------------------
__global__ __launch_bounds__(256) void enc_tables(
    const float* __restrict__ Wq, const float* __restrict__ bq,
    const float* __restrict__ Wk, const float* __restrict__ bk,
    float* __restrict__ EQc, float* __restrict__ EQr,
    float* __restrict__ EKc, float* __restrict__ EKr)
{
    const int c   = blockIdx.x;
    const int ch  = threadIdx.x & 127;
    const int isk = threadIdx.x >> 7;
    const float* W = isk ? Wk : Wq;
    const float* b = isk ? bk : bq;
    const float FSTEP = (float)(3.14 / 200.0);
    float accC = 0.f, accR = 0.f;
    for (int fi = 0; fi < 32; ++fi) {
        float f = (float)fi * FSTEP;
        float a = (float)c * f;
        float s = sinf(a), co = cosf(a);
        accC = fmaf(s,  W[fi * 128 + ch],        accC);
        accC = fmaf(co, W[(32 + fi) * 128 + ch], accC);
        accR = fmaf(s,  W[(64 + fi) * 128 + ch], accR);
        accR = fmaf(co, W[(96 + fi) * 128 + ch], accR);
    }
    accR += b[ch];
    (isk ? EKc : EQc)[c * 128 + ch] = accC;
    (isk ? EKr : EQr)[c * 128 + ch] = accR;
}

// ---------------------------------------------------------------------------
// Kernel 1b: weights -> MFMA-fragment-linear bf16 layout.
// WTf[((j*8 + t16)*4 + ks)*512 + lane*8 + e] = W_j[ks*32 + (lane>>4)*8 + e][t16*16 + (lane&15)]
// j: 0=Wq 1=Wk 2=Wv 3=Wo
// ---------------------------------------------------------------------------
__global__ __launch_bounds__(64) void prep_w(
    const float* __restrict__ Wq, const float* __restrict__ Wk,
    const float* __restrict__ Wv, const float* __restrict__ Wo,
    unsigned short* __restrict__ WTf)
{
    const int bid = blockIdx.x;     // 0..127 = ((j*8+t16)*4+ks)
    const int j = bid >> 5, t16 = (bid >> 2) & 7, ks = bid & 3;
    const int lane = threadIdx.x;   // 0..63
    const int row = t16 * 16 + (lane & 15);      // output channel
    const int k0 = ks * 32 + (lane >> 4) * 8;    // k base
    const float* W = (j == 0) ? Wq : ((j == 1) ? Wk : ((j == 2) ? Wv : Wo));
    unsigned* d32 = (unsigned*)(WTf + (size_t)bid * 512 + lane * 8);
#pragma unroll
    for (int e = 0; e < 4; ++e) {
        float lo = W[(k0 + 2 * e) * 128 + row];
        float hi = W[(k0 + 2 * e + 1) * 128 + row];
        d32[e] = pack2(lo, hi);
    }
}

// ---------------------------------------------------------------------------
// Kernel 2: QKV GEMM via MFMA. 64-token tile staged ONCE, nb-loop over q/k/v.
// Quarter-size obf (16 tokens/pass, 8 KB) -> 24 KB LDS -> 5 blocks/CU
// (launch_bounds(256,5): cap 102 regs vs ~96 used). Grid 2560 = 2 clean rounds.
// ---------------------------------------------------------------------------
__global__ __launch_bounds__(256, 5) void qkv_mfma(
    const float* __restrict__ x,
    const unsigned short* __restrict__ WTf,
    const float* __restrict__ EQc, const float* __restrict__ EQr,
    const float* __restrict__ EKc, const float* __restrict__ EKr,
    const float* __restrict__ bv,
    unsigned short* __restrict__ qb, unsigned short* __restrict__ kb,
    unsigned short* __restrict__ vb)
{
    __shared__ unsigned short xs[64 * 128];   // 16 KB, swizzled [tok][k]
    __shared__ float obf[16 * 128];           //  8 KB, transposed f32 quarter-tile
    const int tid = threadIdx.x;
    const int mb = blockIdx.x;    // 0..2559 (64-token tiles)

    const float* xbase = x + (size_t)mb * (64 * 128);
#pragma unroll
    for (int i = 0; i < 4; ++i) {
        int idx = tid + i * 256;
        int m = idx >> 4, c8 = (idx & 15) << 3;
        float4 f0 = *(const float4*)(xbase + m * 128 + c8);
        float4 f1 = *(const float4*)(xbase + m * 128 + c8 + 4);
        unsigned off = (unsigned)(m * 256 + ((c8 * 2) ^ ((m & 7) << 4)));
        unsigned* d = (unsigned*)((char*)xs + off);
        d[0] = pack2(f0.x, f0.y); d[1] = pack2(f0.z, f0.w);
        d[2] = pack2(f1.x, f1.y); d[3] = pack2(f1.z, f1.w);
    }

    const int lane = tid & 63;
    const int wv4  = tid >> 6;          // wave id 0..3
    const int il = lane & 15, g = lane >> 4;
    const int chb = wv4 << 5;           // wave's 32-channel base
    const int lx = (il & 7) << 4;
    const int rowimg  = (mb >> 1) & 127;
    const int colbase = (mb & 1) * 64;

    __syncthreads();

    for (int nb = 0; nb < 3; ++nb) {
        bf16x8 aw[2][4];
#pragma unroll
        for (int ct = 0; ct < 2; ++ct)
#pragma unroll
            for (int ks = 0; ks < 4; ++ks)
                aw[ct][ks] = *(const bf16x8*)(WTf
                    + (size_t)((nb * 8 + wv4 * 2 + ct) * 4 + ks) * 512 + lane * 8);

        f32x4 acc[4][2] = {};
#pragma unroll
        for (int ks = 0; ks < 4; ++ks) {
            const int kb0 = ks * 64 + g * 16;
#pragma unroll
            for (int mt = 0; mt < 4; ++mt) {
                bf16x8 bx = *(const bf16x8*)((const char*)xs + (mt * 16 + il) * 256 + (kb0 ^ lx));
                acc[mt][0] = __builtin_amdgcn_mfma_f32_16x16x32_bf16(aw[0][ks], bx, acc[mt][0], 0, 0, 0);
                acc[mt][1] = __builtin_amdgcn_mfma_f32_16x16x32_bf16(aw[1][ks], bx, acc[mt][1], 0, 0, 0);
            }
        }

        const float* Ec = (nb == 0) ? EQc : EKc;
        const float* Er = (nb == 0) ? EQr : EKr;
        unsigned short* dstp = (nb == 0) ? qb : ((nb == 1) ? kb : vb);

#pragma unroll
        for (int qt = 0; qt < 4; ++qt) {
            if (!(nb == 0 && qt == 0)) __syncthreads();   // prior ep2 reads done

            // ep1: raw f32 quarter (tokens qt*16..+15) transposed into obf
#pragma unroll
            for (int ct = 0; ct < 2; ++ct) {
                const int ch0 = chb + ct * 16 + (g << 2);
                *(f32x4*)(obf + il * 128 + (ch0 ^ ((il & 7) << 2))) = acc[qt][ct];
            }
            __syncthreads();

            // ep2: coalesced enc add + pack + store (32 lanes = one row)
#pragma unroll
            for (int i = 0; i < 2; ++i) {
                int idx = tid + i * 256;               // 512 chunks of 4 ch
                int ml = idx >> 5, c4 = (idx & 31) << 2;
                int m = qt * 16 + ml;
                f32x4 v = *(const f32x4*)(obf + ml * 128 + (c4 ^ ((ml & 7) << 2)));
                float a0, a1, a2, a3;
                if (nb < 2) {
                    float4 ec = *(const float4*)(Ec + (colbase + m) * 128 + c4);
                    float4 er = *(const float4*)(Er + rowimg * 128 + c4);
                    a0 = ec.x + er.x; a1 = ec.y + er.y;
                    a2 = ec.z + er.z; a3 = ec.w + er.w;
                } else {
                    float4 bvv = *(const float4*)(bv + c4);
                    a0 = bvv.x; a1 = bvv.y; a2 = bvv.z; a3 = bvv.w;
                }
                uint2 o;
                o.x = pack2(v[0] + a0, v[1] + a1);
                o.y = pack2(v[2] + a2, v[3] + a3);
                *(uint2*)(dstp + ((size_t)mb * 64 + m) * 128 + c4) = o;
            }
        }
    }
}

// ---------------------------------------------------------------------------
// Kernel 3: windowed attention + O-proj, full MFMA (round-17 version:
// conflict-free XOR-swizzled 48 KB LDS, 3 blocks/CU).
// ---------------------------------------------------------------------------
__global__ __launch_bounds__(512) void attn_o_mfma(
    const unsigned short* __restrict__ qb, const unsigned short* __restrict__ kb,
    const unsigned short* __restrict__ vb,
    const unsigned short* __restrict__ WTf, const float* __restrict__ bo,
    float* __restrict__ out)
{
    __shared__ __align__(16) char smem[49152];
    const int QOFF = 0, KOFF = 16384, VOFF = 32768;

    const int w = blockIdx.x;       // 0..255
    const int b = blockIdx.y;       // 0..9
    const int wy = w >> 4, wx = w & 15;
    const int g4 = b >> 1;          // bn = 2
    int swy = wy, swx = wx;
    if (g4 == 0)      { if (wy < 15) swy = wy + 1; }   // up
    else if (g4 == 1) { if (wy > 0)  swy = wy - 1; }   // down
    else if (g4 == 2) { if (wx < 15) swx = wx + 1; }   // left
    else if (g4 == 3) { if (wx > 0)  swx = wx - 1; }   // right
    const int tid = threadIdx.x;
    const size_t bbase = (size_t)b * 16384;

    // ---- stage q, k (64 tok x 256 B rows, XOR-swizzled) ----
#pragma unroll
    for (int i = 0; i < 2; ++i) {
        int idx = tid + i * 512;                 // 1024 chunks of 16 B
        int m = idx >> 4, ci = idx & 15;
        int sw = (ci << 4) ^ ((m & 7) << 4);
        int qt = ((wy * 8 + (m >> 3)) << 7) + (wx << 3) + (m & 7);
        uint4 rq = *(const uint4*)(qb + (bbase + qt) * 128 + ci * 8);
        *(uint4*)(smem + QOFF + m * 256 + sw) = rq;
        int kt = ((swy * 8 + (m >> 3)) << 7) + (swx << 3) + (m & 7);
        uint4 rk = *(const uint4*)(kb + (bbase + kt) * 128 + ci * 8);
        *(uint4*)(smem + KOFF + m * 256 + sw) = rk;
    }
    // ---- stage vT (128 ch x 128 B rows, XOR-swizzled), transpose-on-write ----
#pragma unroll
    for (int i = 0; i < 2; ++i) {
        int tok = tid & 63, cs = (tid >> 6) + i * 8;
        int c8 = cs << 3;
        int vt = ((swy * 8 + (tok >> 3)) << 7) + (swx << 3) + (tok & 7);
        uint4 rv = *(const uint4*)(vb + (bbase + vt) * 128 + c8);
        unsigned short e[8] = {
            (unsigned short)rv.x, (unsigned short)(rv.x >> 16),
            (unsigned short)rv.y, (unsigned short)(rv.y >> 16),
            (unsigned short)rv.z, (unsigned short)(rv.z >> 16),
            (unsigned short)rv.w, (unsigned short)(rv.w >> 16) };
#pragma unroll
        for (int t2 = 0; t2 < 8; ++t2) {
            int ch = c8 + t2;
            *(unsigned short*)(smem + VOFF + ch * 128 + ((tok * 2) ^ ((ch & 7) << 4))) = e[t2];
        }
    }
    __syncthreads();   // B1: staging complete

    const int lane = tid & 63;
    const int w8 = tid >> 6;
    const int h = w8 >> 1, half = w8 & 1;
    const int il = lane & 15, g = lane >> 4;
    const int lx = (il & 7) << 4;
    const int cb = h * 64 + g * 16;      // byte offset of lane's 8-ch slice

    // ---- S^T = mfma(k, q), column softmax ----
    bf16x8 ak[4], bq2[2];
#pragma unroll
    for (int mj = 0; mj < 4; ++mj)
        ak[mj] = *(const bf16x8*)(smem + KOFF + (mj * 16 + il) * 256 + (cb ^ lx));
#pragma unroll
    for (int nt = 0; nt < 2; ++nt)
        bq2[nt] = *(const bf16x8*)(smem + QOFF + ((2 * half + nt) * 16 + il) * 256 + (cb ^ lx));
    f32x4 s[4][2] = {};
#pragma unroll
    for (int mj = 0; mj < 4; ++mj)
#pragma unroll
        for (int nt = 0; nt < 2; ++nt)
            s[mj][nt] = __builtin_amdgcn_mfma_f32_16x16x32_bf16(ak[mj], bq2[nt], s[mj][nt], 0, 0, 0);

    const float scale = 0.17677669529663689f;   // 32^-0.5
    float p[4][2][4];
    float csum[2] = {0.f, 0.f};
#pragma unroll
    for (int mj = 0; mj < 4; ++mj)
#pragma unroll
        for (int nt = 0; nt < 2; ++nt)
#pragma unroll
            for (int r = 0; r < 4; ++r) {
                float e = __expf(s[mj][nt][r] * scale);
                p[mj][nt][r] = e;
                csum[nt] += e;
            }
#pragma unroll
    for (int nt = 0; nt < 2; ++nt) {
        csum[nt] += __shfl_xor(csum[nt], 16);
        csum[nt] += __shfl_xor(csum[nt], 32);
    }
    float inv[2] = {1.f / csum[0], 1.f / csum[1]};

    __syncthreads();   // B2: q/k reads done; P may overlay q+k

    // ---- P^T (normalized bf16) -> LDS [i][128 B], swizzled ----
    char* pb = smem + h * 8192;
#pragma unroll
    for (int nt = 0; nt < 2; ++nt) {
        int i = (2 * half + nt) * 16 + il;
#pragma unroll
        for (int mj = 0; mj < 4; ++mj) {
            uint2 o;
            o.x = pack2(p[mj][nt][0] * inv[nt], p[mj][nt][1] * inv[nt]);
            o.y = pack2(p[mj][nt][2] * inv[nt], p[mj][nt][3] * inv[nt]);
            *(uint2*)(pb + i * 128 + ((mj * 32 + g * 8) ^ lx)) = o;
        }
    }
    // no barrier: PV reads only self-written P rows (same wave, same il)

    // ---- aoT = mfma(vT, P^T) ----
    f32x4 apv[2][2] = {};
#pragma unroll
    for (int ks2 = 0; ks2 < 2; ++ks2) {
        bf16x8 av[2], bp[2];
#pragma unroll
        for (int mc = 0; mc < 2; ++mc)
            av[mc] = *(const bf16x8*)(smem + VOFF + (h * 32 + mc * 16 + il) * 128 + ((ks2 * 64 + g * 16) ^ lx));
#pragma unroll
        for (int nt = 0; nt < 2; ++nt)
            bp[nt] = *(const bf16x8*)(pb + ((2 * half + nt) * 16 + il) * 128 + ((ks2 * 64 + g * 16) ^ lx));
#pragma unroll
        for (int mc = 0; mc < 2; ++mc)
#pragma unroll
            for (int nt = 0; nt < 2; ++nt)
                apv[mc][nt] = __builtin_amdgcn_mfma_f32_16x16x32_bf16(av[mc], bp[nt], apv[mc][nt], 0, 0, 0);
    }
    __syncthreads();   // B3: vT/P reads done; ao may overlay vT

    // ---- ao[tok][256 B] bf16 -> LDS, swizzled ----
#pragma unroll
    for (int nt = 0; nt < 2; ++nt) {
        int i = (2 * half + nt) * 16 + il;
#pragma unroll
        for (int mc = 0; mc < 2; ++mc) {
            int c0 = h * 32 + mc * 16 + (g << 2);
            uint2 o;
            o.x = pack2(apv[mc][nt][0], apv[mc][nt][1]);
            o.y = pack2(apv[mc][nt][2], apv[mc][nt][3]);
            *(uint2*)(smem + VOFF + i * 256 + ((c0 * 2) ^ lx)) = o;
        }
    }
    __syncthreads();   // B4: ao complete

    // ---- outT = mfma(WoT, ao); ols overlays q+k (P dead since B3) ----
    bf16x8 awo[4];
#pragma unroll
    for (int ks = 0; ks < 4; ++ks)
        awo[ks] = *(const bf16x8*)(WTf + (size_t)((3 * 8 + w8) * 4 + ks) * 512 + lane * 8);
    f32x4 aco[4] = {};
#pragma unroll
    for (int ks = 0; ks < 4; ++ks) {
#pragma unroll
        for (int nt = 0; nt < 4; ++nt) {
            bf16x8 bao = *(const bf16x8*)(smem + VOFF + (nt * 16 + il) * 256 + ((ks * 64 + g * 16) ^ lx));
            aco[nt] = __builtin_amdgcn_mfma_f32_16x16x32_bf16(awo[ks], bao, aco[nt], 0, 0, 0);
        }
    }

    float bov[4];
#pragma unroll
    for (int r = 0; r < 4; ++r) bov[r] = bo[16 * w8 + (g << 2) + r];
#pragma unroll
    for (int nt = 0; nt < 4; ++nt) {
        int i = nt * 16 + il;
        float4 o4;
        o4.x = aco[nt][0] + bov[0];
        o4.y = aco[nt][1] + bov[1];
        o4.z = aco[nt][2] + bov[2];
        o4.w = aco[nt][3] + bov[3];
        *(float4*)(smem + i * 512 + ((w8 * 64 + g * 16) ^ lx)) = o4;
    }
    __syncthreads();   // B5

    // ---- coalesced f32 store ----
#pragma unroll
    for (int i = 0; i < 4; ++i) {
        int idx = tid + i * 512;                 // 2048 float4 chunks
        int m = idx >> 5, cb16 = (idx & 31) << 4;
        float4 o4 = *(const float4*)(smem + m * 512 + (cb16 ^ ((m & 7) << 4)));
        int t2 = ((wy * 8 + (m >> 3)) << 7) + (wx << 3) + (m & 7);
        *(float4*)(out + (bbase + t2) * 128 + (idx & 31) * 4) = o4;
    }
}

// ---------------------------------------------------------------------------
extern "C" void kernel_launch(void* const* d_in, const int* in_sizes, int n_in,
                              void* d_out, int out_size, void* d_ws, size_t ws_size,
                              hipStream_t stream)
{
    const float* x  = (const float*)d_in[0];
    const float* Wq = (const float*)d_in[1];
    const float* bq = (const float*)d_in[2];
    const float* Wk = (const float*)d_in[3];
    const float* bk = (const float*)d_in[4];
    const float* Wv = (const float*)d_in[5];
    const float* bv = (const float*)d_in[6];
    const float* Wo = (const float*)d_in[7];
    const float* bo = (const float*)d_in[8];

    char* ws = (char*)d_ws;
    float* EQc = (float*)(ws);                       //  65,536 B
    float* EQr = (float*)(ws + 65536);               //  65,536 B
    float* EKc = (float*)(ws + 131072);              //  65,536 B
    float* EKr = (float*)(ws + 196608);              //  65,536 B
    unsigned short* WTf = (unsigned short*)(ws + 262144);  // 131,072 B (fragment-linear)
    unsigned short* qb = (unsigned short*)(ws + 393216);   // 41,943,040 B
    unsigned short* kb = (unsigned short*)(ws + 42336256); // 41,943,040 B
    unsigned short* vb = (unsigned short*)(ws + 84279296); // 41,943,040 B (end 126,222,336)
    float* outp = (float*)d_out;

    enc_tables <<<dim3(128),      256, 0, stream>>>(Wq, bq, Wk, bk, EQc, EQr, EKc, EKr);
    prep_w     <<<dim3(128),       64, 0, stream>>>(Wq, Wk, Wv, Wo, WTf);
    qkv_mfma   <<<dim3(2560),     256, 0, stream>>>(x, WTf, EQc, EQr, EKc, EKr, bv, qb, kb, vb);
    attn_o_mfma<<<dim3(256, 10),  512, 0, stream>>>(qb, kb, vb, WTf, bo, outp);
}

// Round 20
// 104.984 us; speedup vs baseline: 1.3110x; 1.3110x over previous
//
#include <hip/hip_runtime.h>
#include <hip/hip_bf16.h>

typedef __hip_bfloat16 bf16;
typedef short bf16x8 __attribute__((ext_vector_type(8)));
typedef float f32x4 __attribute__((ext_vector_type(4)));

static __device__ __forceinline__ unsigned short f2bf(float f) {
    unsigned u = __float_as_uint(f);
    return (unsigned short)((u + 0x7fffu + ((u >> 16) & 1u)) >> 16);
}
static __device__ __forceinline__ unsigned pack2(float lo, float hi) {
    return (((unsigned)f2bf(hi)) << 16) | (unsigned)f2bf(lo);
}

// ---------------------------------------------------------------------------
// Kernel 1: separable positional-encoding tables (all f32).
// ---------------------------------------------------------------------------
__global__ __launch_bounds__(256) void enc_tables(
    const float* __restrict__ Wq, const float* __restrict__ bq,
    const float* __restrict__ Wk, const float* __restrict__ bk,
    float* __restrict__ EQc, float* __restrict__ EQr,
    float* __restrict__ EKc, float* __restrict__ EKr)
{
    const int c   = blockIdx.x;
    const int ch  = threadIdx.x & 127;
    const int isk = threadIdx.x >> 7;
    const float* W = isk ? Wk : Wq;
    const float* b = isk ? bk : bq;
    const float FSTEP = (float)(3.14 / 200.0);
    float accC = 0.f, accR = 0.f;
    for (int fi = 0; fi < 32; ++fi) {
        float f = (float)fi * FSTEP;
        float a = (float)c * f;
        float s = sinf(a), co = cosf(a);
        accC = fmaf(s,  W[fi * 128 + ch],        accC);
        accC = fmaf(co, W[(32 + fi) * 128 + ch], accC);
        accR = fmaf(s,  W[(64 + fi) * 128 + ch], accR);
        accR = fmaf(co, W[(96 + fi) * 128 + ch], accR);
    }
    accR += b[ch];
    (isk ? EKc : EQc)[c * 128 + ch] = accC;
    (isk ? EKr : EQr)[c * 128 + ch] = accR;
}

// ---------------------------------------------------------------------------
// Kernel 1b: weights -> MFMA-fragment-linear bf16 layout.
// WTf[((j*8 + t16)*4 + ks)*512 + lane*8 + e] = W_j[ks*32 + (lane>>4)*8 + e][t16*16 + (lane&15)]
// j: 0=Wq 1=Wk 2=Wv 3=Wo
// ---------------------------------------------------------------------------
__global__ __launch_bounds__(64) void prep_w(
    const float* __restrict__ Wq, const float* __restrict__ Wk,
    const float* __restrict__ Wv, const float* __restrict__ Wo,
    unsigned short* __restrict__ WTf)
{
    const int bid = blockIdx.x;     // 0..127 = ((j*8+t16)*4+ks)
    const int j = bid >> 5, t16 = (bid >> 2) & 7, ks = bid & 3;
    const int lane = threadIdx.x;   // 0..63
    const int row = t16 * 16 + (lane & 15);      // output channel
    const int k0 = ks * 32 + (lane >> 4) * 8;    // k base
    const float* W = (j == 0) ? Wq : ((j == 1) ? Wk : ((j == 2) ? Wv : Wo));
    unsigned* d32 = (unsigned*)(WTf + (size_t)bid * 512 + lane * 8);
#pragma unroll
    for (int e = 0; e < 4; ++e) {
        float lo = W[(k0 + 2 * e) * 128 + row];
        float hi = W[(k0 + 2 * e + 1) * 128 + row];
        d32[e] = pack2(lo, hi);
    }
}

// ---------------------------------------------------------------------------
// Kernel 2: QKV GEMM via MFMA. 64-token tile staged ONCE, nb-loop over q/k/v.
// Swapped operands D[ch][tok]=mfma(W,x); fragment-linear weight loads.
// f32 half-size obf (32 tokens/pass) -> 32 KB LDS total -> 4 blocks/CU.
// Enc added in ep2 where all loads coalesce; single bf16 rounding.
// (256,4): 128-reg budget — REQUIRED; (256,5) spills (r9/r19 signature).
// ---------------------------------------------------------------------------
__global__ __launch_bounds__(256, 4) void qkv_mfma(
    const float* __restrict__ x,
    const unsigned short* __restrict__ WTf,
    const float* __restrict__ EQc, const float* __restrict__ EQr,
    const float* __restrict__ EKc, const float* __restrict__ EKr,
    const float* __restrict__ bv,
    unsigned short* __restrict__ qb, unsigned short* __restrict__ kb,
    unsigned short* __restrict__ vb)
{
    __shared__ unsigned short xs[64 * 128];   // 16 KB, swizzled [tok][k]
    __shared__ float obf[32 * 128];           // 16 KB, transposed f32 half-tile
    const int tid = threadIdx.x;
    const int mb = blockIdx.x;    // 0..2559 (64-token tiles)

    const float* xbase = x + (size_t)mb * (64 * 128);
#pragma unroll
    for (int i = 0; i < 4; ++i) {
        int idx = tid + i * 256;
        int m = idx >> 4, c8 = (idx & 15) << 3;
        float4 f0 = *(const float4*)(xbase + m * 128 + c8);
        float4 f1 = *(const float4*)(xbase + m * 128 + c8 + 4);
        unsigned off = (unsigned)(m * 256 + ((c8 * 2) ^ ((m & 7) << 4)));
        unsigned* d = (unsigned*)((char*)xs + off);
        d[0] = pack2(f0.x, f0.y); d[1] = pack2(f0.z, f0.w);
        d[2] = pack2(f1.x, f1.y); d[3] = pack2(f1.z, f1.w);
    }

    const int lane = tid & 63;
    const int wv4  = tid >> 6;
    const int il = lane & 15, g = lane >> 4;
    const int chb = wv4 << 5;
    const int lx = (il & 7) << 4;
    const int rowimg  = (mb >> 1) & 127;
    const int colbase = (mb & 1) * 64;

    __syncthreads();

    for (int nb = 0; nb < 3; ++nb) {
        bf16x8 aw[2][4];
#pragma unroll
        for (int ct = 0; ct < 2; ++ct)
#pragma unroll
            for (int ks = 0; ks < 4; ++ks)
                aw[ct][ks] = *(const bf16x8*)(WTf
                    + (size_t)((nb * 8 + wv4 * 2 + ct) * 4 + ks) * 512 + lane * 8);

        f32x4 acc[4][2] = {};
#pragma unroll
        for (int ks = 0; ks < 4; ++ks) {
            const int kb0 = ks * 64 + g * 16;
#pragma unroll
            for (int mt = 0; mt < 4; ++mt) {
                bf16x8 bx = *(const bf16x8*)((const char*)xs + (mt * 16 + il) * 256 + (kb0 ^ lx));
                acc[mt][0] = __builtin_amdgcn_mfma_f32_16x16x32_bf16(aw[0][ks], bx, acc[mt][0], 0, 0, 0);
                acc[mt][1] = __builtin_amdgcn_mfma_f32_16x16x32_bf16(aw[1][ks], bx, acc[mt][1], 0, 0, 0);
            }
        }

        const float* Ec = (nb == 0) ? EQc : EKc;
        const float* Er = (nb == 0) ? EQr : EKr;
        unsigned short* dstp = (nb == 0) ? qb : ((nb == 1) ? kb : vb);

#pragma unroll
        for (int half = 0; half < 2; ++half) {
            if (nb > 0 || half > 0) __syncthreads();

#pragma unroll
            for (int ct = 0; ct < 2; ++ct) {
                const int ch0 = chb + ct * 16 + (g << 2);
#pragma unroll
                for (int mt2 = 0; mt2 < 2; ++mt2) {
                    const int ml = mt2 * 16 + il;
                    *(f32x4*)(obf + ml * 128 + (ch0 ^ ((ml & 7) << 2))) =
                        acc[half * 2 + mt2][ct];
                }
            }
            __syncthreads();

#pragma unroll
            for (int i = 0; i < 4; ++i) {
                int idx = tid + i * 256;
                int ml = idx >> 5, c4 = (idx & 31) << 2;
                int m = half * 32 + ml;
                f32x4 v = *(const f32x4*)(obf + ml * 128 + (c4 ^ ((ml & 7) << 2)));
                float a0, a1, a2, a3;
                if (nb < 2) {
                    float4 ec = *(const float4*)(Ec + (colbase + m) * 128 + c4);
                    float4 er = *(const float4*)(Er + rowimg * 128 + c4);
                    a0 = ec.x + er.x; a1 = ec.y + er.y;
                    a2 = ec.z + er.z; a3 = ec.w + er.w;
                } else {
                    float4 bvv = *(const float4*)(bv + c4);
                    a0 = bvv.x; a1 = bvv.y; a2 = bvv.z; a3 = bvv.w;
                }
                uint2 o;
                o.x = pack2(v[0] + a0, v[1] + a1);
                o.y = pack2(v[2] + a2, v[3] + a3);
                *(uint2*)(dstp + ((size_t)mb * 64 + m) * 128 + c4) = o;
            }
        }
    }
}

// ---------------------------------------------------------------------------
// Kernel 3: windowed attention + O-proj, full MFMA. Conflict-free
// XOR-swizzled 48 KB LDS (rows 256 B / 128 B, key (row&7)<<4), 3 blocks/CU.
// ---------------------------------------------------------------------------
__global__ __launch_bounds__(512) void attn_o_mfma(
    const unsigned short* __restrict__ qb, const unsigned short* __restrict__ kb,
    const unsigned short* __restrict__ vb,
    const unsigned short* __restrict__ WTf, const float* __restrict__ bo,
    float* __restrict__ out)
{
    __shared__ __align__(16) char smem[49152];
    const int QOFF = 0, KOFF = 16384, VOFF = 32768;

    const int w = blockIdx.x;       // 0..255
    const int b = blockIdx.y;       // 0..9
    const int wy = w >> 4, wx = w & 15;
    const int g4 = b >> 1;          // bn = 2
    int swy = wy, swx = wx;
    if (g4 == 0)      { if (wy < 15) swy = wy + 1; }   // up
    else if (g4 == 1) { if (wy > 0)  swy = wy - 1; }   // down
    else if (g4 == 2) { if (wx < 15) swx = wx + 1; }   // left
    else if (g4 == 3) { if (wx > 0)  swx = wx - 1; }   // right
    const int tid = threadIdx.x;
    const size_t bbase = (size_t)b * 16384;

    // ---- stage q, k (64 tok x 256 B rows, XOR-swizzled) ----
#pragma unroll
    for (int i = 0; i < 2; ++i) {
        int idx = tid + i * 512;                 // 1024 chunks of 16 B
        int m = idx >> 4, ci = idx & 15;
        int sw = (ci << 4) ^ ((m & 7) << 4);
        int qt = ((wy * 8 + (m >> 3)) << 7) + (wx << 3) + (m & 7);
        uint4 rq = *(const uint4*)(qb + (bbase + qt) * 128 + ci * 8);
        *(uint4*)(smem + QOFF + m * 256 + sw) = rq;
        int kt = ((swy * 8 + (m >> 3)) << 7) + (swx << 3) + (m & 7);
        uint4 rk = *(const uint4*)(kb + (bbase + kt) * 128 + ci * 8);
        *(uint4*)(smem + KOFF + m * 256 + sw) = rk;
    }
    // ---- stage vT (128 ch x 128 B rows, XOR-swizzled), transpose-on-write ----
#pragma unroll
    for (int i = 0; i < 2; ++i) {
        int tok = tid & 63, cs = (tid >> 6) + i * 8;
        int c8 = cs << 3;
        int vt = ((swy * 8 + (tok >> 3)) << 7) + (swx << 3) + (tok & 7);
        uint4 rv = *(const uint4*)(vb + (bbase + vt) * 128 + c8);
        unsigned short e[8] = {
            (unsigned short)rv.x, (unsigned short)(rv.x >> 16),
            (unsigned short)rv.y, (unsigned short)(rv.y >> 16),
            (unsigned short)rv.z, (unsigned short)(rv.z >> 16),
            (unsigned short)rv.w, (unsigned short)(rv.w >> 16) };
#pragma unroll
        for (int t2 = 0; t2 < 8; ++t2) {
            int ch = c8 + t2;
            *(unsigned short*)(smem + VOFF + ch * 128 + ((tok * 2) ^ ((ch & 7) << 4))) = e[t2];
        }
    }
    __syncthreads();   // B1: staging complete

    const int lane = tid & 63;
    const int w8 = tid >> 6;
    const int h = w8 >> 1, half = w8 & 1;
    const int il = lane & 15, g = lane >> 4;
    const int lx = (il & 7) << 4;
    const int cb = h * 64 + g * 16;      // byte offset of lane's 8-ch slice

    // ---- S^T = mfma(k, q), column softmax ----
    bf16x8 ak[4], bq2[2];
#pragma unroll
    for (int mj = 0; mj < 4; ++mj)
        ak[mj] = *(const bf16x8*)(smem + KOFF + (mj * 16 + il) * 256 + (cb ^ lx));
#pragma unroll
    for (int nt = 0; nt < 2; ++nt)
        bq2[nt] = *(const bf16x8*)(smem + QOFF + ((2 * half + nt) * 16 + il) * 256 + (cb ^ lx));
    f32x4 s[4][2] = {};
#pragma unroll
    for (int mj = 0; mj < 4; ++mj)
#pragma unroll
        for (int nt = 0; nt < 2; ++nt)
            s[mj][nt] = __builtin_amdgcn_mfma_f32_16x16x32_bf16(ak[mj], bq2[nt], s[mj][nt], 0, 0, 0);

    const float scale = 0.17677669529663689f;   // 32^-0.5
    float p[4][2][4];
    float csum[2] = {0.f, 0.f};
#pragma unroll
    for (int mj = 0; mj < 4; ++mj)
#pragma unroll
        for (int nt = 0; nt < 2; ++nt)
#pragma unroll
            for (int r = 0; r < 4; ++r) {
                float e = __expf(s[mj][nt][r] * scale);
                p[mj][nt][r] = e;
                csum[nt] += e;
            }
#pragma unroll
    for (int nt = 0; nt < 2; ++nt) {
        csum[nt] += __shfl_xor(csum[nt], 16);
        csum[nt] += __shfl_xor(csum[nt], 32);
    }
    float inv[2] = {1.f / csum[0], 1.f / csum[1]};

    __syncthreads();   // B2: q/k reads done; P may overlay q+k

    // ---- P^T (normalized bf16) -> LDS [i][128 B], swizzled ----
    char* pb = smem + h * 8192;
#pragma unroll
    for (int nt = 0; nt < 2; ++nt) {
        int i = (2 * half + nt) * 16 + il;
#pragma unroll
        for (int mj = 0; mj < 4; ++mj) {
            uint2 o;
            o.x = pack2(p[mj][nt][0] * inv[nt], p[mj][nt][1] * inv[nt]);
            o.y = pack2(p[mj][nt][2] * inv[nt], p[mj][nt][3] * inv[nt]);
            *(uint2*)(pb + i * 128 + ((mj * 32 + g * 8) ^ lx)) = o;
        }
    }
    // no barrier: PV reads only self-written P rows (same wave, same il)

    // ---- aoT = mfma(vT, P^T) ----
    f32x4 apv[2][2] = {};
#pragma unroll
    for (int ks2 = 0; ks2 < 2; ++ks2) {
        bf16x8 av[2], bp[2];
#pragma unroll
        for (int mc = 0; mc < 2; ++mc)
            av[mc] = *(const bf16x8*)(smem + VOFF + (h * 32 + mc * 16 + il) * 128 + ((ks2 * 64 + g * 16) ^ lx));
#pragma unroll
        for (int nt = 0; nt < 2; ++nt)
            bp[nt] = *(const bf16x8*)(pb + ((2 * half + nt) * 16 + il) * 128 + ((ks2 * 64 + g * 16) ^ lx));
#pragma unroll
        for (int mc = 0; mc < 2; ++mc)
#pragma unroll
            for (int nt = 0; nt < 2; ++nt)
                apv[mc][nt] = __builtin_amdgcn_mfma_f32_16x16x32_bf16(av[mc], bp[nt], apv[mc][nt], 0, 0, 0);
    }
    __syncthreads();   // B3: vT/P reads done; ao may overlay vT

    // ---- ao[tok][256 B] bf16 -> LDS, swizzled ----
#pragma unroll
    for (int nt = 0; nt < 2; ++nt) {
        int i = (2 * half + nt) * 16 + il;
#pragma unroll
        for (int mc = 0; mc < 2; ++mc) {
            int c0 = h * 32 + mc * 16 + (g << 2);
            uint2 o;
            o.x = pack2(apv[mc][nt][0], apv[mc][nt][1]);
            o.y = pack2(apv[mc][nt][2], apv[mc][nt][3]);
            *(uint2*)(smem + VOFF + i * 256 + ((c0 * 2) ^ lx)) = o;
        }
    }
    __syncthreads();   // B4: ao complete

    // ---- outT = mfma(WoT, ao); ols overlays q+k (P dead since B3) ----
    bf16x8 awo[4];
#pragma unroll
    for (int ks = 0; ks < 4; ++ks)
        awo[ks] = *(const bf16x8*)(WTf + (size_t)((3 * 8 + w8) * 4 + ks) * 512 + lane * 8);
    f32x4 aco[4] = {};
#pragma unroll
    for (int ks = 0; ks < 4; ++ks) {
#pragma unroll
        for (int nt = 0; nt < 4; ++nt) {
            bf16x8 bao = *(const bf16x8*)(smem + VOFF + (nt * 16 + il) * 256 + ((ks * 64 + g * 16) ^ lx));
            aco[nt] = __builtin_amdgcn_mfma_f32_16x16x32_bf16(awo[ks], bao, aco[nt], 0, 0, 0);
        }
    }

    float bov[4];
#pragma unroll
    for (int r = 0; r < 4; ++r) bov[r] = bo[16 * w8 + (g << 2) + r];
#pragma unroll
    for (int nt = 0; nt < 4; ++nt) {
        int i = nt * 16 + il;
        float4 o4;
        o4.x = aco[nt][0] + bov[0];
        o4.y = aco[nt][1] + bov[1];
        o4.z = aco[nt][2] + bov[2];
        o4.w = aco[nt][3] + bov[3];
        *(float4*)(smem + i * 512 + ((w8 * 64 + g * 16) ^ lx)) = o4;
    }
    __syncthreads();   // B5

    // ---- coalesced f32 store ----
#pragma unroll
    for (int i = 0; i < 4; ++i) {
        int idx = tid + i * 512;                 // 2048 float4 chunks
        int m = idx >> 5, cb16 = (idx & 31) << 4;
        float4 o4 = *(const float4*)(smem + m * 512 + (cb16 ^ ((m & 7) << 4)));
        int t2 = ((wy * 8 + (m >> 3)) << 7) + (wx << 3) + (m & 7);
        *(float4*)(out + (bbase + t2) * 128 + (idx & 31) * 4) = o4;
    }
}

// ---------------------------------------------------------------------------
extern "C" void kernel_launch(void* const* d_in, const int* in_sizes, int n_in,
                              void* d_out, int out_size, void* d_ws, size_t ws_size,
                              hipStream_t stream)
{
    const float* x  = (const float*)d_in[0];
    const float* Wq = (const float*)d_in[1];
    const float* bq = (const float*)d_in[2];
    const float* Wk = (const float*)d_in[3];
    const float* bk = (const float*)d_in[4];
    const float* Wv = (const float*)d_in[5];
    const float* bv = (const float*)d_in[6];
    const float* Wo = (const float*)d_in[7];
    const float* bo = (const float*)d_in[8];

    char* ws = (char*)d_ws;
    float* EQc = (float*)(ws);                       //  65,536 B
    float* EQr = (float*)(ws + 65536);               //  65,536 B
    float* EKc = (float*)(ws + 131072);              //  65,536 B
    float* EKr = (float*)(ws + 196608);              //  65,536 B
    unsigned short* WTf = (unsigned short*)(ws + 262144);  // 131,072 B (fragment-linear)
    unsigned short* qb = (unsigned short*)(ws + 393216);   // 41,943,040 B
    unsigned short* kb = (unsigned short*)(ws + 42336256); // 41,943,040 B
    unsigned short* vb = (unsigned short*)(ws + 84279296); // 41,943,040 B (end 126,222,336)
    float* outp = (float*)d_out;

    enc_tables <<<dim3(128),      256, 0, stream>>>(Wq, bq, Wk, bk, EQc, EQr, EKc, EKr);
    prep_w     <<<dim3(128),       64, 0, stream>>>(Wq, Wk, Wv, Wo, WTf);
    qkv_mfma   <<<dim3(2560),     256, 0, stream>>>(x, WTf, EQc, EQr, EKc, EKr, bv, qb, kb, vb);
    attn_o_mfma<<<dim3(256, 10),  512, 0, stream>>>(qb, kb, vb, WTf, bo, outp);
}